// Round 5
// baseline (248.949 us; speedup 1.0000x reference)
//
#include <hip/hip_runtime.h>

typedef __bf16 bf16x8 __attribute__((ext_vector_type(8)));
typedef float f32x4 __attribute__((ext_vector_type(4)));
typedef unsigned short u16;
typedef unsigned int u32;
typedef u16 u16x8 __attribute__((ext_vector_type(8)));

__device__ __forceinline__ u16 f2bf(float f) {
    union { float f; u32 u; } x{f};
    u32 r = x.u + 0x7FFFu + ((x.u >> 16) & 1u);  // RNE
    return (u16)(r >> 16);
}

__device__ __forceinline__ float ex2(float x) {
#if __has_builtin(__builtin_amdgcn_exp2f)
    return __builtin_amdgcn_exp2f(x);
#else
    return __expf(x * 0.6931471805599453f);
#endif
}

// async global->LDS, 16B per lane; LDS dest = wave-uniform base + lane*16
#define GLD16(g, l)                                                            \
    __builtin_amdgcn_global_load_lds(                                          \
        (const __attribute__((address_space(1))) u32*)(g),                     \
        (__attribute__((address_space(3))) u32*)(l), 16, 0, 0)

// ---------------------------------------------------------------------------
// Both weight transposes in one kernel.
// blocks 0..1727: w_qkv [768][2304] -> WqT [2304][768]
// blocks 1728..2303: w_proj [768][768] -> WpT [768][768]
// ---------------------------------------------------------------------------
__global__ __launch_bounds__(256) void prep_weights(
    const float* __restrict__ wq, const float* __restrict__ wp,
    u16* __restrict__ WqT, u16* __restrict__ WpT)
{
    __shared__ u16 tile[32][33];
    int id = blockIdx.x;
    const float* src; u16* dst; int R, C, bx, by;
    if (id < 1728) { src = wq; dst = WqT; R = 768; C = 2304; bx = (id % 72) * 32; by = (id / 72) * 32; }
    else { id -= 1728; src = wp; dst = WpT; R = 768; C = 768; bx = (id % 24) * 32; by = (id / 24) * 32; }
    int x = threadIdx.x & 31, y = threadIdx.x >> 5;
    #pragma unroll
    for (int i = 0; i < 32; i += 8)
        tile[y + i][x] = f2bf(src[(size_t)(by + y + i) * C + bx + x]);
    __syncthreads();
    #pragma unroll
    for (int i = 0; i < 32; i += 8)
        dst[(size_t)(bx + y + i) * R + by + x] = tile[x][y + i];
}

// ---------------------------------------------------------------------------
// Fused QKV GEMM: QKV[M][2304] = X[M][768](fp32) * WqT[2304][768]^T
// 128x128 tile, 4 waves 2x2, 16x16x32 MFMA, BK=32.
// A staged from fp32 with in-register bf16 convert (padded LDS, conflict-free
// reads); B staged via global_load_lds width=16 (unpadded lane-linear).
// Q columns (<768) pre-scaled by qscale.
// V-section blocks (bn>=1536): MFMA operands swapped -> C^T in standard
// C-layout -> epilogue writes Vt[bh][d][n] directly (transpose for free).
// ---------------------------------------------------------------------------
template <int K>
__global__ __launch_bounds__(256) void gemm_qkv(
    const float* __restrict__ X,    // [M][K] fp32
    const u16* __restrict__ Wt,     // [2304][K] bf16
    u16* __restrict__ QKV,          // [M][2304] (Q,K sections only)
    u16* __restrict__ Vt,           // [96][64][1024]
    float qscale)
{
    __shared__ u16 As[128][40];                 // padded (80B rows, 16B aligned)
    __shared__ __align__(16) u16 Bs[128 * 32];  // unpadded lane-linear (DMA)

    int tid = threadIdx.x;
    int wave = tid >> 6, lane = tid & 63;
    int quad = lane >> 4, l16 = lane & 15;
    int wm = (wave >> 1) * 64, wn = (wave & 1) * 64;
    int bm = blockIdx.y * 128, bn = blockIdx.x * 128;
    bool vsec = (bn >= 1536);

    f32x4 acc[4][4] = {};

    // A staging: thread covers row r=tid>>1, 16 k-elems at (tid&1)*16
    int r = tid >> 1, cgA = (tid & 1) * 16;
    const float* Ap = X + (size_t)(bm + r) * K + cgA;

    // B staging: GLD16, instr (wave,j): lane l -> row wave*32+j*16+(l>>2), cg (l&3)*8
    int srow = lane >> 2, scg = (lane & 3) * 8;
    const u16* Bp = Wt + (size_t)(bn + wave * 32 + srow) * K + scg;
    const int w0 = (wave * 32) * 32;
    const int w1 = (wave * 32 + 16) * 32;
    const size_t rstep = (size_t)16 * K;

    for (int k0 = 0; k0 < K; k0 += 32) {
        GLD16(Bp + k0,         &Bs[w0]);
        GLD16(Bp + k0 + rstep, &Bs[w1]);
        float4 f0 = *(const float4*)(Ap + k0);
        float4 f1 = *(const float4*)(Ap + k0 + 4);
        float4 f2 = *(const float4*)(Ap + k0 + 8);
        float4 f3 = *(const float4*)(Ap + k0 + 12);
        u16x8 lo = { f2bf(f0.x), f2bf(f0.y), f2bf(f0.z), f2bf(f0.w),
                     f2bf(f1.x), f2bf(f1.y), f2bf(f1.z), f2bf(f1.w) };
        u16x8 hi = { f2bf(f2.x), f2bf(f2.y), f2bf(f2.z), f2bf(f2.w),
                     f2bf(f3.x), f2bf(f3.y), f2bf(f3.z), f2bf(f3.w) };
        *(u16x8*)&As[r][cgA]     = lo;
        *(u16x8*)&As[r][cgA + 8] = hi;
        __syncthreads();

        bf16x8 af[4], bfr[4];
        #pragma unroll
        for (int i = 0; i < 4; i++) {
            af[i]  = *(const bf16x8*)&As[wm + i * 16 + l16][quad * 8];
            bfr[i] = *(const bf16x8*)&Bs[(wn + i * 16 + l16) * 32 + quad * 8];
        }
        if (!vsec) {
            #pragma unroll
            for (int mi = 0; mi < 4; mi++)
                #pragma unroll
                for (int ni = 0; ni < 4; ni++)
                    acc[mi][ni] = __builtin_amdgcn_mfma_f32_16x16x32_bf16(af[mi], bfr[ni], acc[mi][ni], 0, 0, 0);
        } else {
            #pragma unroll
            for (int mi = 0; mi < 4; mi++)
                #pragma unroll
                for (int ni = 0; ni < 4; ni++)
                    acc[mi][ni] = __builtin_amdgcn_mfma_f32_16x16x32_bf16(bfr[ni], af[mi], acc[mi][ni], 0, 0, 0);
        }
        __syncthreads();
    }

    if (!vsec) {
        #pragma unroll
        for (int mi = 0; mi < 4; mi++) {
            #pragma unroll
            for (int ni = 0; ni < 4; ni++) {
                #pragma unroll
                for (int rg = 0; rg < 4; rg++) {
                    int row = bm + wm + mi * 16 + quad * 4 + rg;
                    int col = bn + wn + ni * 16 + l16;
                    float sc = (col < 768) ? qscale : 1.0f;
                    QKV[(size_t)row * 2304 + col] = f2bf(acc[mi][ni][rg] * sc);
                }
            }
        }
    } else {
        // acc[mi][ni] holds C^T: row' = Wt-row (d), col' = X-row (n)
        #pragma unroll
        for (int mi = 0; mi < 4; mi++) {
            #pragma unroll
            for (int ni = 0; ni < 4; ni++) {
                #pragma unroll
                for (int rg = 0; rg < 4; rg++) {
                    int d = (bn - 1536) + wn + ni * 16 + quad * 4 + rg;   // 0..767
                    int ng = bm + wm + mi * 16 + l16;
                    int b = ng >> 10, n = ng & 1023, h = d >> 6;
                    Vt[((size_t)(b * 12 + h) * 64 + (d & 63)) * 1024 + n] = f2bf(acc[mi][ni][rg]);
                }
            }
        }
    }
}

// ---------------------------------------------------------------------------
// Output projection GEMM (round-3 structure): out = Ctx * WpT^T + bias (fp32)
// ---------------------------------------------------------------------------
template <int K>
__global__ __launch_bounds__(256) void gemm_proj(
    const u16* __restrict__ A,    // [M][K] bf16
    const u16* __restrict__ Bt,   // [N][K] bf16
    float* __restrict__ Cp,       // [M][N] fp32
    const float* __restrict__ bias,
    int M, int N)
{
    __shared__ __align__(16) u16 As[128 * 32];
    __shared__ __align__(16) u16 Bs[128 * 32];

    int tid = threadIdx.x;
    int wave = tid >> 6, lane = tid & 63;
    int quad = lane >> 4, l16 = lane & 15;
    int wm = (wave >> 1) * 64, wn = (wave & 1) * 64;
    int bm = blockIdx.y * 128, bn = blockIdx.x * 128;

    f32x4 acc[4][4] = {};

    int srow = lane >> 2, scg = (lane & 3) * 8;
    const u16* Aptr = A + (size_t)(bm + wave * 32 + srow) * K + scg;
    const u16* Bptr = Bt + (size_t)(bn + wave * 32 + srow) * K + scg;
    const int w0 = (wave * 32) * 32;
    const int w1 = (wave * 32 + 16) * 32;
    const size_t rstep = (size_t)16 * K;

    for (int k0 = 0; k0 < K; k0 += 32) {
        GLD16(Aptr + k0,         &As[w0]);
        GLD16(Aptr + k0 + rstep, &As[w1]);
        GLD16(Bptr + k0,         &Bs[w0]);
        GLD16(Bptr + k0 + rstep, &Bs[w1]);
        __syncthreads();

        bf16x8 af[4], bfr[4];
        #pragma unroll
        for (int i = 0; i < 4; i++) {
            af[i]  = *(const bf16x8*)&As[(wm + i * 16 + l16) * 32 + quad * 8];
            bfr[i] = *(const bf16x8*)&Bs[(wn + i * 16 + l16) * 32 + quad * 8];
        }
        #pragma unroll
        for (int mi = 0; mi < 4; mi++)
            #pragma unroll
            for (int ni = 0; ni < 4; ni++)
                acc[mi][ni] = __builtin_amdgcn_mfma_f32_16x16x32_bf16(af[mi], bfr[ni], acc[mi][ni], 0, 0, 0);
        __syncthreads();
    }

    #pragma unroll
    for (int mi = 0; mi < 4; mi++) {
        #pragma unroll
        for (int ni = 0; ni < 4; ni++) {
            #pragma unroll
            for (int rg = 0; rg < 4; rg++) {
                int row = bm + wm + mi * 16 + quad * 4 + rg;
                int col = bn + wn + ni * 16 + l16;
                Cp[(size_t)row * N + col] = acc[mi][ni][rg] + bias[col];
            }
        }
    }
}

// ---------------------------------------------------------------------------
// Flash attention: grid (16 q-tiles, 96 b*h), 256 thr = 4 waves x 16 Q rows.
// fixed-max softmax (scores bounded), row sums via ones-MFMA, double-buffered
// async K/V staging, XOR-swizzled unpadded LDS, 1 barrier/iter.
// Q pre-scaled by 0.125*log2e in GEMM1 epilogue; p = exp2(qk) directly.
// ---------------------------------------------------------------------------
__global__ __launch_bounds__(256, 4) void attn_kernel(
    const u16* __restrict__ qkv,
    const u16* __restrict__ Vt,
    u16* __restrict__ ctx)
{
    __shared__ __align__(16) u16 Ks[2][4096];   // 2 x 64key x 64d (swizzled)
    __shared__ __align__(16) u16 Vs[2][4096];   // 2 x 64d x 64key (swizzled)
    __shared__ __align__(16) u16 Ps[4096];      // 4 waves x 16q x 64key (swizzled)

    int qt = blockIdx.x;            // 0..15
    int bh = blockIdx.y;            // 0..95
    int b = bh / 12, h = bh % 12;
    int tid = threadIdx.x;
    int wave = tid >> 6, lane = tid & 63;
    int quad = lane >> 4, l16 = lane & 15;

    int sw8 = (quad ^ (l16 & 7)) * 8;

    // Q fragments (A-layout, pre-scaled), kept in registers
    int qrow = qt * 64 + wave * 16 + l16;
    const u16* qbase = qkv + (size_t)(b * 1024 + qrow) * 2304 + h * 64;
    bf16x8 qf0 = *(const bf16x8*)(qbase + quad * 8);
    bf16x8 qf1 = *(const bf16x8*)(qbase + 32 + quad * 8);

    // staging addresses (row = lane>>3, dgroup = (lane&7) ^ row)
    int srow = lane >> 3;
    int scol = (lane & 7) ^ srow;
    const u16* kA = qkv + (size_t)(b * 1024 + wave * 16 + srow) * 2304 + 768 + h * 64 + scol * 8;
    const u16* vA = Vt + ((size_t)bh * 64 + wave * 16 + srow) * 1024 + scol * 8;

    bf16x8 ones;
    #pragma unroll
    for (int j = 0; j < 8; j++) ((u16*)&ones)[j] = 0x3F80;  // bf16 1.0

    f32x4 o[4] = {};
    f32x4 lsum = {};

    // prologue: stage tile 0 into buf 0
    {
        GLD16(kA,            &Ks[0][(wave * 2 + 0) * 512]);
        GLD16(kA + 8 * 2304, &Ks[0][(wave * 2 + 1) * 512]);
        GLD16(vA,            &Vs[0][(wave * 2 + 0) * 512]);
        GLD16(vA + 8 * 1024, &Vs[0][(wave * 2 + 1) * 512]);
    }

    #pragma unroll 2
    for (int kt = 0; kt < 16; kt++) {
        int buf = kt & 1;
        __syncthreads();   // drains vmcnt(0): buf is populated

        if (kt < 15) {     // prefetch next tile into the other buffer
            const u16* k0 = kA + (size_t)(kt + 1) * (64 * 2304);
            const u16* v0 = vA + (size_t)(kt + 1) * 64;
            GLD16(k0,            &Ks[buf ^ 1][(wave * 2 + 0) * 512]);
            GLD16(k0 + 8 * 2304, &Ks[buf ^ 1][(wave * 2 + 1) * 512]);
            GLD16(v0,            &Vs[buf ^ 1][(wave * 2 + 0) * 512]);
            GLD16(v0 + 8 * 1024, &Vs[buf ^ 1][(wave * 2 + 1) * 512]);
        }

        // S = Qs K^T
        f32x4 s[4];
        #pragma unroll
        for (int nb = 0; nb < 4; nb++) {
            int rbase = (nb * 16 + l16) * 64;
            bf16x8 kf0 = *(const bf16x8*)&Ks[buf][rbase + sw8];
            bf16x8 kf1 = *(const bf16x8*)&Ks[buf][rbase + (sw8 ^ 32)];
            f32x4 z = {};
            z = __builtin_amdgcn_mfma_f32_16x16x32_bf16(qf0, kf0, z, 0, 0, 0);
            z = __builtin_amdgcn_mfma_f32_16x16x32_bf16(qf1, kf1, z, 0, 0, 0);
            s[nb] = z;
        }

        // P = exp2(S), pack to bf16, store to per-wave swizzled Ps
        #pragma unroll
        for (int nb = 0; nb < 4; nb++) {
            #pragma unroll
            for (int rg = 0; rg < 4; rg++) {
                float p = ex2(s[nb][rg]);
                union { float f; u32 u; } c{p};
                u16 pb = (u16)((c.u + 0x8000u) >> 16);  // round-half-up, p>=0
                int row = quad * 4 + rg;
                int cgr = (nb * 2 + (l16 >> 3)) ^ (row & 7);
                Ps[wave * 1024 + row * 64 + cgr * 8 + (l16 & 7)] = pb;
            }
        }
        asm volatile("s_waitcnt lgkmcnt(0)" ::: "memory");

        bf16x8 pf0 = *(const bf16x8*)&Ps[wave * 1024 + l16 * 64 + sw8];
        bf16x8 pf1 = *(const bf16x8*)&Ps[wave * 1024 + l16 * 64 + (sw8 ^ 32)];

        // row sums: l += P . 1
        lsum = __builtin_amdgcn_mfma_f32_16x16x32_bf16(pf0, ones, lsum, 0, 0, 0);
        lsum = __builtin_amdgcn_mfma_f32_16x16x32_bf16(pf1, ones, lsum, 0, 0, 0);

        // O += P V
        #pragma unroll
        for (int db = 0; db < 4; db++) {
            int rbase = (db * 16 + l16) * 64;
            bf16x8 vf0 = *(const bf16x8*)&Vs[buf][rbase + sw8];
            bf16x8 vf1 = *(const bf16x8*)&Vs[buf][rbase + (sw8 ^ 32)];
            o[db] = __builtin_amdgcn_mfma_f32_16x16x32_bf16(pf0, vf0, o[db], 0, 0, 0);
            o[db] = __builtin_amdgcn_mfma_f32_16x16x32_bf16(pf1, vf1, o[db], 0, 0, 0);
        }
    }

    // epilogue: O / l -> ctx bf16
    float rl[4];
    #pragma unroll
    for (int rg = 0; rg < 4; rg++) rl[rg] = 1.0f / lsum[rg];
    #pragma unroll
    for (int db = 0; db < 4; db++) {
        #pragma unroll
        for (int rg = 0; rg < 4; rg++) {
            int row = qt * 64 + wave * 16 + quad * 4 + rg;
            int col = h * 64 + db * 16 + l16;
            ctx[(size_t)(b * 1024 + row) * 768 + col] = f2bf(o[db][rg] * rl[rg]);
        }
    }
}

// ---------------------------------------------------------------------------
extern "C" void kernel_launch(void* const* d_in, const int* in_sizes, int n_in,
                              void* d_out, int out_size, void* d_ws, size_t ws_size,
                              hipStream_t stream) {
    const float* x      = (const float*)d_in[0];  // [8,1024,768]
    const float* w_qkv  = (const float*)d_in[1];  // [768,2304]
    const float* w_proj = (const float*)d_in[2];  // [768,768]
    const float* b_proj = (const float*)d_in[3];  // [768]
    float* out = (float*)d_out;

    const int BN = 8192;     // B*N
    const int C = 768, C3 = 2304;
    const float CE = 0.18033688011112042f;  // 0.125 * log2(e)

    u16* Wqkv_t  = (u16*)d_ws;                       // 2304*768
    u16* Wproj_t = Wqkv_t + (size_t)C3 * C;          // 768*768
    u16* QKV     = Wproj_t + (size_t)C * C;          // 8192*2304 (Q,K used)
    u16* Vt      = QKV + (size_t)BN * C3;            // 96*64*1024
    u16* Ctx     = Vt + (size_t)96 * 64 * 1024;      // 8192*768

    prep_weights<<<2304, 256, 0, stream>>>(w_qkv, w_proj, Wqkv_t, Wproj_t);

    gemm_qkv<768><<<dim3(C3 / 128, BN / 128), 256, 0, stream>>>(
        x, Wqkv_t, QKV, Vt, CE);

    attn_kernel<<<dim3(16, 96), 256, 0, stream>>>(QKV, Vt, Ctx);

    gemm_proj<768><<<dim3(C / 128, BN / 128), 256, 0, stream>>>(
        Ctx, Wproj_t, out, b_proj, BN, C);
}

// Round 6
// 213.441 us; speedup vs baseline: 1.1664x; 1.1664x over previous
//
#include <hip/hip_runtime.h>

typedef __bf16 bf16x8 __attribute__((ext_vector_type(8)));
typedef float f32x4 __attribute__((ext_vector_type(4)));
typedef unsigned short u16;
typedef unsigned int u32;
typedef u16 u16x4 __attribute__((ext_vector_type(4)));

__device__ __forceinline__ u16 f2bf(float f) {
    union { float f; u32 u; } x{f};
    u32 r = x.u + 0x7FFFu + ((x.u >> 16) & 1u);  // RNE
    return (u16)(r >> 16);
}

__device__ __forceinline__ float ex2(float x) {
#if __has_builtin(__builtin_amdgcn_exp2f)
    return __builtin_amdgcn_exp2f(x);
#else
    return __expf(x * 0.6931471805599453f);
#endif
}

// async global->LDS, 16B per lane; LDS dest = wave-uniform base + lane*16
#define GLD16(g, l)                                                            \
    __builtin_amdgcn_global_load_lds(                                          \
        (const __attribute__((address_space(1))) u32*)(g),                     \
        (__attribute__((address_space(3))) u32*)(l), 16, 0, 0)

// ---------------------------------------------------------------------------
// Elementwise fp32 -> bf16 convert (x)
// ---------------------------------------------------------------------------
__global__ void convert_bf16(const float* __restrict__ src, u16* __restrict__ dst, int n4) {
    int i = blockIdx.x * blockDim.x + threadIdx.x;
    if (i < n4) {
        float4 f = *(const float4*)(src + (size_t)i * 4);
        u16x4 u = { f2bf(f.x), f2bf(f.y), f2bf(f.z), f2bf(f.w) };
        *(u16x4*)(dst + (size_t)i * 4) = u;
    }
}

// ---------------------------------------------------------------------------
// Both weight transposes in one kernel.
// blocks 0..1727: w_qkv [768][2304] -> WqT [2304][768]
// blocks 1728..2303: w_proj [768][768] -> WpT [768][768]
// ---------------------------------------------------------------------------
__global__ __launch_bounds__(256) void prep_weights(
    const float* __restrict__ wq, const float* __restrict__ wp,
    u16* __restrict__ WqT, u16* __restrict__ WpT)
{
    __shared__ u16 tile[32][33];
    int id = blockIdx.x;
    const float* src; u16* dst; int R, C, bx, by;
    if (id < 1728) { src = wq; dst = WqT; R = 768; C = 2304; bx = (id % 72) * 32; by = (id / 72) * 32; }
    else { id -= 1728; src = wp; dst = WpT; R = 768; C = 768; bx = (id % 24) * 32; by = (id / 24) * 32; }
    int x = threadIdx.x & 31, y = threadIdx.x >> 5;
    #pragma unroll
    for (int i = 0; i < 32; i += 8)
        tile[y + i][x] = f2bf(src[(size_t)(by + y + i) * C + bx + x]);
    __syncthreads();
    #pragma unroll
    for (int i = 0; i < 32; i += 8)
        dst[(size_t)(bx + y + i) * R + by + x] = tile[x][y + i];
}

// ---------------------------------------------------------------------------
// QKV GEMM: [8192][2304] = Xb[8192][768](bf16) * WqT[2304][768]^T
// 128x128 tile, 4 waves 2x2, 16x16x32 MFMA, BK=64 (two 32-k halves per
// barrier pair -> 12 iters, 24 barriers instead of 48). Both operands staged
// via global_load_lds width=16 into unpadded row-major [128][64] LDS.
// Q columns (<768) pre-scaled by qscale (folds 0.125*log2e into Q).
// V-section blocks (bn>=1536): MFMA operands swapped -> C^T in C-layout ->
// epilogue writes Vt[bh][d][n] directly (transpose for free).
// ---------------------------------------------------------------------------
template <int K>
__global__ __launch_bounds__(256) void gemm_qkv(
    const u16* __restrict__ A,      // [M][K] bf16 (Xb)
    const u16* __restrict__ Wt,     // [2304][K] bf16
    u16* __restrict__ QKV,          // [M][2304] (Q,K sections written)
    u16* __restrict__ Vt,           // [96][64][1024]
    float qscale)
{
    __shared__ __align__(16) u16 As[128 * 64];  // row-major [row][64], no pad
    __shared__ __align__(16) u16 Bs[128 * 64];

    int tid = threadIdx.x;
    int wave = tid >> 6, lane = tid & 63;
    int quad = lane >> 4, l16 = lane & 15;
    int wm = (wave >> 1) * 64, wn = (wave & 1) * 64;
    int bm = blockIdx.y * 128, bn = blockIdx.x * 128;
    bool vsec = (bn >= 1536);

    f32x4 acc[4][4] = {};

    // staging: instr (wave, j=0..3): lane l -> row wave*32 + j*8 + (l>>3),
    // col granule (l&7)*8; LDS dest = base + l*16 (lane-linear, row 128B).
    int srow = lane >> 3;
    int scg = (lane & 7) * 8;
    const u16* Ap = A + (size_t)(bm + wave * 32 + srow) * K + scg;
    const u16* Bp = Wt + (size_t)(bn + wave * 32 + srow) * K + scg;

    for (int k0 = 0; k0 < K; k0 += 64) {
        #pragma unroll
        for (int j = 0; j < 4; j++) {
            GLD16(Ap + k0 + (size_t)j * 8 * K, &As[(wave * 32 + j * 8) * 64]);
            GLD16(Bp + k0 + (size_t)j * 8 * K, &Bs[(wave * 32 + j * 8) * 64]);
        }
        __syncthreads();   // drains vmcnt(0): tiles populated

        #pragma unroll
        for (int h = 0; h < 2; h++) {
            bf16x8 af[4], bfr[4];
            #pragma unroll
            for (int i = 0; i < 4; i++) {
                af[i]  = *(const bf16x8*)&As[(wm + i * 16 + l16) * 64 + h * 32 + quad * 8];
                bfr[i] = *(const bf16x8*)&Bs[(wn + i * 16 + l16) * 64 + h * 32 + quad * 8];
            }
            if (!vsec) {
                #pragma unroll
                for (int mi = 0; mi < 4; mi++)
                    #pragma unroll
                    for (int ni = 0; ni < 4; ni++)
                        acc[mi][ni] = __builtin_amdgcn_mfma_f32_16x16x32_bf16(af[mi], bfr[ni], acc[mi][ni], 0, 0, 0);
            } else {
                #pragma unroll
                for (int mi = 0; mi < 4; mi++)
                    #pragma unroll
                    for (int ni = 0; ni < 4; ni++)
                        acc[mi][ni] = __builtin_amdgcn_mfma_f32_16x16x32_bf16(bfr[ni], af[mi], acc[mi][ni], 0, 0, 0);
            }
        }
        __syncthreads();
    }

    if (!vsec) {
        #pragma unroll
        for (int mi = 0; mi < 4; mi++) {
            #pragma unroll
            for (int ni = 0; ni < 4; ni++) {
                #pragma unroll
                for (int rg = 0; rg < 4; rg++) {
                    int row = bm + wm + mi * 16 + quad * 4 + rg;
                    int col = bn + wn + ni * 16 + l16;
                    float sc = (col < 768) ? qscale : 1.0f;
                    QKV[(size_t)row * 2304 + col] = f2bf(acc[mi][ni][rg] * sc);
                }
            }
        }
    } else {
        // acc[mi][ni] holds C^T: row' = Wt-row (d), col' = X-row (n)
        #pragma unroll
        for (int mi = 0; mi < 4; mi++) {
            #pragma unroll
            for (int ni = 0; ni < 4; ni++) {
                #pragma unroll
                for (int rg = 0; rg < 4; rg++) {
                    int d = (bn - 1536) + wn + ni * 16 + quad * 4 + rg;   // 0..767
                    int ng = bm + wm + mi * 16 + l16;
                    int b = ng >> 10, n = ng & 1023, h = d >> 6;
                    Vt[((size_t)(b * 12 + h) * 64 + (d & 63)) * 1024 + n] = f2bf(acc[mi][ni][rg]);
                }
            }
        }
    }
}

// ---------------------------------------------------------------------------
// Output projection GEMM: out[M][768] = Ctx * WpT^T + bias (fp32 out), BK=64.
// ---------------------------------------------------------------------------
template <int K>
__global__ __launch_bounds__(256) void gemm_proj(
    const u16* __restrict__ A,    // [M][K] bf16
    const u16* __restrict__ Bt,   // [N][K] bf16
    float* __restrict__ Cp,       // [M][N] fp32
    const float* __restrict__ bias,
    int M, int N)
{
    __shared__ __align__(16) u16 As[128 * 64];
    __shared__ __align__(16) u16 Bs[128 * 64];

    int tid = threadIdx.x;
    int wave = tid >> 6, lane = tid & 63;
    int quad = lane >> 4, l16 = lane & 15;
    int wm = (wave >> 1) * 64, wn = (wave & 1) * 64;
    int bm = blockIdx.y * 128, bn = blockIdx.x * 128;

    f32x4 acc[4][4] = {};

    int srow = lane >> 3;
    int scg = (lane & 7) * 8;
    const u16* Ap = A + (size_t)(bm + wave * 32 + srow) * K + scg;
    const u16* Bp = Bt + (size_t)(bn + wave * 32 + srow) * K + scg;

    for (int k0 = 0; k0 < K; k0 += 64) {
        #pragma unroll
        for (int j = 0; j < 4; j++) {
            GLD16(Ap + k0 + (size_t)j * 8 * K, &As[(wave * 32 + j * 8) * 64]);
            GLD16(Bp + k0 + (size_t)j * 8 * K, &Bs[(wave * 32 + j * 8) * 64]);
        }
        __syncthreads();

        #pragma unroll
        for (int h = 0; h < 2; h++) {
            bf16x8 af[4], bfr[4];
            #pragma unroll
            for (int i = 0; i < 4; i++) {
                af[i]  = *(const bf16x8*)&As[(wm + i * 16 + l16) * 64 + h * 32 + quad * 8];
                bfr[i] = *(const bf16x8*)&Bs[(wn + i * 16 + l16) * 64 + h * 32 + quad * 8];
            }
            #pragma unroll
            for (int mi = 0; mi < 4; mi++)
                #pragma unroll
                for (int ni = 0; ni < 4; ni++)
                    acc[mi][ni] = __builtin_amdgcn_mfma_f32_16x16x32_bf16(af[mi], bfr[ni], acc[mi][ni], 0, 0, 0);
        }
        __syncthreads();
    }

    #pragma unroll
    for (int mi = 0; mi < 4; mi++) {
        #pragma unroll
        for (int ni = 0; ni < 4; ni++) {
            #pragma unroll
            for (int rg = 0; rg < 4; rg++) {
                int row = bm + wm + mi * 16 + quad * 4 + rg;
                int col = bn + wn + ni * 16 + l16;
                Cp[(size_t)row * N + col] = acc[mi][ni][rg] + bias[col];
            }
        }
    }
}

// ---------------------------------------------------------------------------
// Flash attention: grid (16 q-tiles, 96 b*h), 256 thr = 4 waves x 16 Q rows.
// fixed-max softmax (scores bounded), row sums via ones-MFMA, double-buffered
// async K/V staging, XOR-swizzled unpadded LDS, 1 barrier/iter.
// Q pre-scaled by 0.125*log2e in GEMM1 epilogue; p = exp2(qk) directly.
// ---------------------------------------------------------------------------
__global__ __launch_bounds__(256, 4) void attn_kernel(
    const u16* __restrict__ qkv,
    const u16* __restrict__ Vt,
    u16* __restrict__ ctx)
{
    __shared__ __align__(16) u16 Ks[2][4096];   // 2 x 64key x 64d (swizzled)
    __shared__ __align__(16) u16 Vs[2][4096];   // 2 x 64d x 64key (swizzled)
    __shared__ __align__(16) u16 Ps[4096];      // 4 waves x 16q x 64key (swizzled)

    int qt = blockIdx.x;            // 0..15
    int bh = blockIdx.y;            // 0..95
    int b = bh / 12, h = bh % 12;
    int tid = threadIdx.x;
    int wave = tid >> 6, lane = tid & 63;
    int quad = lane >> 4, l16 = lane & 15;

    int sw8 = (quad ^ (l16 & 7)) * 8;

    // Q fragments (A-layout, pre-scaled), kept in registers
    int qrow = qt * 64 + wave * 16 + l16;
    const u16* qbase = qkv + (size_t)(b * 1024 + qrow) * 2304 + h * 64;
    bf16x8 qf0 = *(const bf16x8*)(qbase + quad * 8);
    bf16x8 qf1 = *(const bf16x8*)(qbase + 32 + quad * 8);

    // staging addresses (row = lane>>3, dgroup = (lane&7) ^ row)
    int srow = lane >> 3;
    int scol = (lane & 7) ^ srow;
    const u16* kA = qkv + (size_t)(b * 1024 + wave * 16 + srow) * 2304 + 768 + h * 64 + scol * 8;
    const u16* vA = Vt + ((size_t)bh * 64 + wave * 16 + srow) * 1024 + scol * 8;

    bf16x8 ones;
    #pragma unroll
    for (int j = 0; j < 8; j++) ((u16*)&ones)[j] = 0x3F80;  // bf16 1.0

    f32x4 o[4] = {};
    f32x4 lsum = {};

    // prologue: stage tile 0 into buf 0
    {
        GLD16(kA,            &Ks[0][(wave * 2 + 0) * 512]);
        GLD16(kA + 8 * 2304, &Ks[0][(wave * 2 + 1) * 512]);
        GLD16(vA,            &Vs[0][(wave * 2 + 0) * 512]);
        GLD16(vA + 8 * 1024, &Vs[0][(wave * 2 + 1) * 512]);
    }

    #pragma unroll 2
    for (int kt = 0; kt < 16; kt++) {
        int buf = kt & 1;
        __syncthreads();   // drains vmcnt(0): buf is populated

        if (kt < 15) {     // prefetch next tile into the other buffer
            const u16* k0 = kA + (size_t)(kt + 1) * (64 * 2304);
            const u16* v0 = vA + (size_t)(kt + 1) * 64;
            GLD16(k0,            &Ks[buf ^ 1][(wave * 2 + 0) * 512]);
            GLD16(k0 + 8 * 2304, &Ks[buf ^ 1][(wave * 2 + 1) * 512]);
            GLD16(v0,            &Vs[buf ^ 1][(wave * 2 + 0) * 512]);
            GLD16(v0 + 8 * 1024, &Vs[buf ^ 1][(wave * 2 + 1) * 512]);
        }

        // S = Qs K^T
        f32x4 s[4];
        #pragma unroll
        for (int nb = 0; nb < 4; nb++) {
            int rbase = (nb * 16 + l16) * 64;
            bf16x8 kf0 = *(const bf16x8*)&Ks[buf][rbase + sw8];
            bf16x8 kf1 = *(const bf16x8*)&Ks[buf][rbase + (sw8 ^ 32)];
            f32x4 z = {};
            z = __builtin_amdgcn_mfma_f32_16x16x32_bf16(qf0, kf0, z, 0, 0, 0);
            z = __builtin_amdgcn_mfma_f32_16x16x32_bf16(qf1, kf1, z, 0, 0, 0);
            s[nb] = z;
        }

        // P = exp2(S), pack to bf16, store to per-wave swizzled Ps
        #pragma unroll
        for (int nb = 0; nb < 4; nb++) {
            #pragma unroll
            for (int rg = 0; rg < 4; rg++) {
                float p = ex2(s[nb][rg]);
                union { float f; u32 u; } c{p};
                u16 pb = (u16)((c.u + 0x8000u) >> 16);  // round-half-up, p>=0
                int row = quad * 4 + rg;
                int cgr = (nb * 2 + (l16 >> 3)) ^ (row & 7);
                Ps[wave * 1024 + row * 64 + cgr * 8 + (l16 & 7)] = pb;
            }
        }
        asm volatile("s_waitcnt lgkmcnt(0)" ::: "memory");

        bf16x8 pf0 = *(const bf16x8*)&Ps[wave * 1024 + l16 * 64 + sw8];
        bf16x8 pf1 = *(const bf16x8*)&Ps[wave * 1024 + l16 * 64 + (sw8 ^ 32)];

        // row sums: l += P . 1
        lsum = __builtin_amdgcn_mfma_f32_16x16x32_bf16(pf0, ones, lsum, 0, 0, 0);
        lsum = __builtin_amdgcn_mfma_f32_16x16x32_bf16(pf1, ones, lsum, 0, 0, 0);

        // O += P V
        #pragma unroll
        for (int db = 0; db < 4; db++) {
            int rbase = (db * 16 + l16) * 64;
            bf16x8 vf0 = *(const bf16x8*)&Vs[buf][rbase + sw8];
            bf16x8 vf1 = *(const bf16x8*)&Vs[buf][rbase + (sw8 ^ 32)];
            o[db] = __builtin_amdgcn_mfma_f32_16x16x32_bf16(pf0, vf0, o[db], 0, 0, 0);
            o[db] = __builtin_amdgcn_mfma_f32_16x16x32_bf16(pf1, vf1, o[db], 0, 0, 0);
        }
    }

    // epilogue: O / l -> ctx bf16
    float rl[4];
    #pragma unroll
    for (int rg = 0; rg < 4; rg++) rl[rg] = 1.0f / lsum[rg];
    #pragma unroll
    for (int db = 0; db < 4; db++) {
        #pragma unroll
        for (int rg = 0; rg < 4; rg++) {
            int row = qt * 64 + wave * 16 + quad * 4 + rg;
            int col = h * 64 + db * 16 + l16;
            ctx[(size_t)(b * 1024 + row) * 768 + col] = f2bf(o[db][rg] * rl[rg]);
        }
    }
}

// ---------------------------------------------------------------------------
extern "C" void kernel_launch(void* const* d_in, const int* in_sizes, int n_in,
                              void* d_out, int out_size, void* d_ws, size_t ws_size,
                              hipStream_t stream) {
    const float* x      = (const float*)d_in[0];  // [8,1024,768]
    const float* w_qkv  = (const float*)d_in[1];  // [768,2304]
    const float* w_proj = (const float*)d_in[2];  // [768,768]
    const float* b_proj = (const float*)d_in[3];  // [768]
    float* out = (float*)d_out;

    const int BN = 8192;     // B*N
    const int C = 768, C3 = 2304;
    const float CE = 0.18033688011112042f;  // 0.125 * log2(e)

    u16* Xb      = (u16*)d_ws;                       // 8192*768
    u16* Wqkv_t  = Xb + (size_t)BN * C;              // 2304*768
    u16* Wproj_t = Wqkv_t + (size_t)C3 * C;          // 768*768
    u16* QKV     = Wproj_t + (size_t)C * C;          // 8192*2304 (Q,K used)
    u16* Vt      = QKV + (size_t)BN * C3;            // 96*64*1024
    u16* Ctx     = Vt + (size_t)96 * 64 * 1024;      // 8192*768

    convert_bf16<<<(BN * C / 4 + 255) / 256, 256, 0, stream>>>(x, Xb, BN * C / 4);
    prep_weights<<<2304, 256, 0, stream>>>(w_qkv, w_proj, Wqkv_t, Wproj_t);

    gemm_qkv<768><<<dim3(C3 / 128, BN / 128), 256, 0, stream>>>(
        Xb, Wqkv_t, QKV, Vt, CE);

    attn_kernel<<<dim3(16, 96), 256, 0, stream>>>(QKV, Vt, Ctx);

    gemm_proj<768><<<dim3(C / 128, BN / 128), 256, 0, stream>>>(
        Ctx, Wproj_t, out, b_proj, BN, C);
}

// Round 7
// 199.634 us; speedup vs baseline: 1.2470x; 1.0692x over previous
//
#include <hip/hip_runtime.h>

typedef __bf16 bf16x8 __attribute__((ext_vector_type(8)));
typedef float f32x4 __attribute__((ext_vector_type(4)));
typedef unsigned short u16;
typedef unsigned int u32;
typedef u16 u16x4 __attribute__((ext_vector_type(4)));

__device__ __forceinline__ u16 f2bf(float f) {
    union { float f; u32 u; } x{f};
    u32 r = x.u + 0x7FFFu + ((x.u >> 16) & 1u);  // RNE
    return (u16)(r >> 16);
}

__device__ __forceinline__ float ex2(float x) {
#if __has_builtin(__builtin_amdgcn_exp2f)
    return __builtin_amdgcn_exp2f(x);
#else
    return __expf(x * 0.6931471805599453f);
#endif
}

// async global->LDS, 16B per lane; LDS dest = wave-uniform base + lane*16
#define GLD16(g, l)                                                            \
    __builtin_amdgcn_global_load_lds(                                          \
        (const __attribute__((address_space(1))) u32*)(g),                     \
        (__attribute__((address_space(3))) u32*)(l), 16, 0, 0)

// ---------------------------------------------------------------------------
// Elementwise fp32 -> bf16 convert (x)
// ---------------------------------------------------------------------------
__global__ void convert_bf16(const float* __restrict__ src, u16* __restrict__ dst, int n4) {
    int i = blockIdx.x * blockDim.x + threadIdx.x;
    if (i < n4) {
        float4 f = *(const float4*)(src + (size_t)i * 4);
        u16x4 u = { f2bf(f.x), f2bf(f.y), f2bf(f.z), f2bf(f.w) };
        *(u16x4*)(dst + (size_t)i * 4) = u;
    }
}

// ---------------------------------------------------------------------------
// Both weight transposes in one kernel.
// blocks 0..1727: w_qkv [768][2304] -> WqT [2304][768]
// blocks 1728..2303: w_proj [768][768] -> WpT [768][768]
// ---------------------------------------------------------------------------
__global__ __launch_bounds__(256) void prep_weights(
    const float* __restrict__ wq, const float* __restrict__ wp,
    u16* __restrict__ WqT, u16* __restrict__ WpT)
{
    __shared__ u16 tile[32][33];
    int id = blockIdx.x;
    const float* src; u16* dst; int R, C, bx, by;
    if (id < 1728) { src = wq; dst = WqT; R = 768; C = 2304; bx = (id % 72) * 32; by = (id / 72) * 32; }
    else { id -= 1728; src = wp; dst = WpT; R = 768; C = 768; bx = (id % 24) * 32; by = (id / 24) * 32; }
    int x = threadIdx.x & 31, y = threadIdx.x >> 5;
    #pragma unroll
    for (int i = 0; i < 32; i += 8)
        tile[y + i][x] = f2bf(src[(size_t)(by + y + i) * C + bx + x]);
    __syncthreads();
    #pragma unroll
    for (int i = 0; i < 32; i += 8)
        dst[(size_t)(bx + y + i) * R + by + x] = tile[x][y + i];
}

// ---------------------------------------------------------------------------
// QKV GEMM: [8192][2304] = Xb[8192][768](bf16) * WqT[2304][768]^T
// 128x128 tile, 4 waves 2x2, 16x16x32 MFMA, BK=64 (12 iters, 24 barriers).
// XOR-granule-swizzled LDS: LDS granule g of row r holds global granule
// g^(r&7); staging lane l reads global granule (l&7)^(l>>3); fragment reads
// use granule (h*4+quad)^(l16&7) -> 2 lanes/granule at SAME address
// (broadcast, conflict-free) spread over all 32 banks.
// Q columns (<768) pre-scaled by qscale (folds 0.125*log2e into Q).
// V-section blocks (bn>=1536): MFMA operands swapped -> C^T in C-layout ->
// epilogue writes Vt[bh][d][n] directly (transpose for free).
// ---------------------------------------------------------------------------
template <int K>
__global__ __launch_bounds__(256) void gemm_qkv(
    const u16* __restrict__ A,      // [M][K] bf16 (Xb)
    const u16* __restrict__ Wt,     // [2304][K] bf16
    u16* __restrict__ QKV,          // [M][2304] (Q,K sections written)
    u16* __restrict__ Vt,           // [96][64][1024]
    float qscale)
{
    __shared__ __align__(16) u16 As[128 * 64];  // row-major [row][64], swizzled
    __shared__ __align__(16) u16 Bs[128 * 64];

    int tid = threadIdx.x;
    int wave = tid >> 6, lane = tid & 63;
    int quad = lane >> 4, l16 = lane & 15;
    int wm = (wave >> 1) * 64, wn = (wave & 1) * 64;
    int bm = blockIdx.y * 128, bn = blockIdx.x * 128;
    bool vsec = (bn >= 1536);

    f32x4 acc[4][4] = {};

    // staging: instr (wave, j=0..3): lane l -> row wave*32 + j*8 + (l>>3),
    // global col granule (l&7)^(l>>3); LDS dest = base + l*16 (lane-linear).
    int srow = lane >> 3;
    int scg = ((lane & 7) ^ srow) * 8;
    const u16* Ap = A + (size_t)(bm + wave * 32 + srow) * K + scg;
    const u16* Bp = Wt + (size_t)(bn + wave * 32 + srow) * K + scg;

    // swizzled fragment granule offsets (u16 units) per h-half
    int fg0 = (((0 * 4 + quad) ^ (l16 & 7)) * 8);
    int fg1 = (((1 * 4 + quad) ^ (l16 & 7)) * 8);

    for (int k0 = 0; k0 < K; k0 += 64) {
        #pragma unroll
        for (int j = 0; j < 4; j++) {
            GLD16(Ap + k0 + (size_t)j * 8 * K, &As[(wave * 32 + j * 8) * 64]);
            GLD16(Bp + k0 + (size_t)j * 8 * K, &Bs[(wave * 32 + j * 8) * 64]);
        }
        __syncthreads();   // drains vmcnt(0): tiles populated

        #pragma unroll
        for (int h = 0; h < 2; h++) {
            int fg = h ? fg1 : fg0;
            bf16x8 af[4], bfr[4];
            #pragma unroll
            for (int i = 0; i < 4; i++) {
                af[i]  = *(const bf16x8*)&As[(wm + i * 16 + l16) * 64 + fg];
                bfr[i] = *(const bf16x8*)&Bs[(wn + i * 16 + l16) * 64 + fg];
            }
            if (!vsec) {
                #pragma unroll
                for (int mi = 0; mi < 4; mi++)
                    #pragma unroll
                    for (int ni = 0; ni < 4; ni++)
                        acc[mi][ni] = __builtin_amdgcn_mfma_f32_16x16x32_bf16(af[mi], bfr[ni], acc[mi][ni], 0, 0, 0);
            } else {
                #pragma unroll
                for (int mi = 0; mi < 4; mi++)
                    #pragma unroll
                    for (int ni = 0; ni < 4; ni++)
                        acc[mi][ni] = __builtin_amdgcn_mfma_f32_16x16x32_bf16(bfr[ni], af[mi], acc[mi][ni], 0, 0, 0);
            }
        }
        __syncthreads();
    }

    if (!vsec) {
        #pragma unroll
        for (int mi = 0; mi < 4; mi++) {
            #pragma unroll
            for (int ni = 0; ni < 4; ni++) {
                #pragma unroll
                for (int rg = 0; rg < 4; rg++) {
                    int row = bm + wm + mi * 16 + quad * 4 + rg;
                    int col = bn + wn + ni * 16 + l16;
                    float sc = (col < 768) ? qscale : 1.0f;
                    QKV[(size_t)row * 2304 + col] = f2bf(acc[mi][ni][rg] * sc);
                }
            }
        }
    } else {
        // acc[mi][ni] holds C^T: row' = Wt-row (d), col' = X-row (n)
        #pragma unroll
        for (int mi = 0; mi < 4; mi++) {
            #pragma unroll
            for (int ni = 0; ni < 4; ni++) {
                #pragma unroll
                for (int rg = 0; rg < 4; rg++) {
                    int d = (bn - 1536) + wn + ni * 16 + quad * 4 + rg;   // 0..767
                    int ng = bm + wm + mi * 16 + l16;
                    int b = ng >> 10, n = ng & 1023, h = d >> 6;
                    Vt[((size_t)(b * 12 + h) * 64 + (d & 63)) * 1024 + n] = f2bf(acc[mi][ni][rg]);
                }
            }
        }
    }
}

// ---------------------------------------------------------------------------
// Output projection GEMM: out[M][768] = Ctx * WpT^T + bias (fp32 out), BK=64,
// same XOR-granule swizzle.
// ---------------------------------------------------------------------------
template <int K>
__global__ __launch_bounds__(256) void gemm_proj(
    const u16* __restrict__ A,    // [M][K] bf16
    const u16* __restrict__ Bt,   // [N][K] bf16
    float* __restrict__ Cp,       // [M][N] fp32
    const float* __restrict__ bias,
    int M, int N)
{
    __shared__ __align__(16) u16 As[128 * 64];
    __shared__ __align__(16) u16 Bs[128 * 64];

    int tid = threadIdx.x;
    int wave = tid >> 6, lane = tid & 63;
    int quad = lane >> 4, l16 = lane & 15;
    int wm = (wave >> 1) * 64, wn = (wave & 1) * 64;
    int bm = blockIdx.y * 128, bn = blockIdx.x * 128;

    f32x4 acc[4][4] = {};

    int srow = lane >> 3;
    int scg = ((lane & 7) ^ srow) * 8;
    const u16* Ap = A + (size_t)(bm + wave * 32 + srow) * K + scg;
    const u16* Bp = Bt + (size_t)(bn + wave * 32 + srow) * K + scg;

    int fg0 = (((0 * 4 + quad) ^ (l16 & 7)) * 8);
    int fg1 = (((1 * 4 + quad) ^ (l16 & 7)) * 8);

    for (int k0 = 0; k0 < K; k0 += 64) {
        #pragma unroll
        for (int j = 0; j < 4; j++) {
            GLD16(Ap + k0 + (size_t)j * 8 * K, &As[(wave * 32 + j * 8) * 64]);
            GLD16(Bp + k0 + (size_t)j * 8 * K, &Bs[(wave * 32 + j * 8) * 64]);
        }
        __syncthreads();

        #pragma unroll
        for (int h = 0; h < 2; h++) {
            int fg = h ? fg1 : fg0;
            bf16x8 af[4], bfr[4];
            #pragma unroll
            for (int i = 0; i < 4; i++) {
                af[i]  = *(const bf16x8*)&As[(wm + i * 16 + l16) * 64 + fg];
                bfr[i] = *(const bf16x8*)&Bs[(wn + i * 16 + l16) * 64 + fg];
            }
            #pragma unroll
            for (int mi = 0; mi < 4; mi++)
                #pragma unroll
                for (int ni = 0; ni < 4; ni++)
                    acc[mi][ni] = __builtin_amdgcn_mfma_f32_16x16x32_bf16(af[mi], bfr[ni], acc[mi][ni], 0, 0, 0);
        }
        __syncthreads();
    }

    #pragma unroll
    for (int mi = 0; mi < 4; mi++) {
        #pragma unroll
        for (int ni = 0; ni < 4; ni++) {
            #pragma unroll
            for (int rg = 0; rg < 4; rg++) {
                int row = bm + wm + mi * 16 + quad * 4 + rg;
                int col = bn + wn + ni * 16 + l16;
                Cp[(size_t)row * N + col] = acc[mi][ni][rg] + bias[col];
            }
        }
    }
}

// ---------------------------------------------------------------------------
// Flash attention: grid (16 q-tiles, 96 b*h), 256 thr = 4 waves x 16 Q rows.
// fixed-max softmax (scores bounded), row sums via ones-MFMA, double-buffered
// async K/V staging, XOR-swizzled unpadded LDS, 1 barrier/iter.
// Q pre-scaled by 0.125*log2e in GEMM1 epilogue; p = exp2(qk) directly.
// ---------------------------------------------------------------------------
__global__ __launch_bounds__(256, 4) void attn_kernel(
    const u16* __restrict__ qkv,
    const u16* __restrict__ Vt,
    u16* __restrict__ ctx)
{
    __shared__ __align__(16) u16 Ks[2][4096];   // 2 x 64key x 64d (swizzled)
    __shared__ __align__(16) u16 Vs[2][4096];   // 2 x 64d x 64key (swizzled)
    __shared__ __align__(16) u16 Ps[4096];      // 4 waves x 16q x 64key (swizzled)

    int qt = blockIdx.x;            // 0..15
    int bh = blockIdx.y;            // 0..95
    int b = bh / 12, h = bh % 12;
    int tid = threadIdx.x;
    int wave = tid >> 6, lane = tid & 63;
    int quad = lane >> 4, l16 = lane & 15;

    int sw8 = (quad ^ (l16 & 7)) * 8;

    // Q fragments (A-layout, pre-scaled), kept in registers
    int qrow = qt * 64 + wave * 16 + l16;
    const u16* qbase = qkv + (size_t)(b * 1024 + qrow) * 2304 + h * 64;
    bf16x8 qf0 = *(const bf16x8*)(qbase + quad * 8);
    bf16x8 qf1 = *(const bf16x8*)(qbase + 32 + quad * 8);

    // staging addresses (row = lane>>3, dgroup = (lane&7) ^ row)
    int srow = lane >> 3;
    int scol = (lane & 7) ^ srow;
    const u16* kA = qkv + (size_t)(b * 1024 + wave * 16 + srow) * 2304 + 768 + h * 64 + scol * 8;
    const u16* vA = Vt + ((size_t)bh * 64 + wave * 16 + srow) * 1024 + scol * 8;

    bf16x8 ones;
    #pragma unroll
    for (int j = 0; j < 8; j++) ((u16*)&ones)[j] = 0x3F80;  // bf16 1.0

    f32x4 o[4] = {};
    f32x4 lsum = {};

    // prologue: stage tile 0 into buf 0
    {
        GLD16(kA,            &Ks[0][(wave * 2 + 0) * 512]);
        GLD16(kA + 8 * 2304, &Ks[0][(wave * 2 + 1) * 512]);
        GLD16(vA,            &Vs[0][(wave * 2 + 0) * 512]);
        GLD16(vA + 8 * 1024, &Vs[0][(wave * 2 + 1) * 512]);
    }

    #pragma unroll 2
    for (int kt = 0; kt < 16; kt++) {
        int buf = kt & 1;
        __syncthreads();   // drains vmcnt(0): buf is populated

        if (kt < 15) {     // prefetch next tile into the other buffer
            const u16* k0 = kA + (size_t)(kt + 1) * (64 * 2304);
            const u16* v0 = vA + (size_t)(kt + 1) * 64;
            GLD16(k0,            &Ks[buf ^ 1][(wave * 2 + 0) * 512]);
            GLD16(k0 + 8 * 2304, &Ks[buf ^ 1][(wave * 2 + 1) * 512]);
            GLD16(v0,            &Vs[buf ^ 1][(wave * 2 + 0) * 512]);
            GLD16(v0 + 8 * 1024, &Vs[buf ^ 1][(wave * 2 + 1) * 512]);
        }

        // S = Qs K^T
        f32x4 s[4];
        #pragma unroll
        for (int nb = 0; nb < 4; nb++) {
            int rbase = (nb * 16 + l16) * 64;
            bf16x8 kf0 = *(const bf16x8*)&Ks[buf][rbase + sw8];
            bf16x8 kf1 = *(const bf16x8*)&Ks[buf][rbase + (sw8 ^ 32)];
            f32x4 z = {};
            z = __builtin_amdgcn_mfma_f32_16x16x32_bf16(qf0, kf0, z, 0, 0, 0);
            z = __builtin_amdgcn_mfma_f32_16x16x32_bf16(qf1, kf1, z, 0, 0, 0);
            s[nb] = z;
        }

        // P = exp2(S), pack to bf16, store to per-wave swizzled Ps
        #pragma unroll
        for (int nb = 0; nb < 4; nb++) {
            #pragma unroll
            for (int rg = 0; rg < 4; rg++) {
                float p = ex2(s[nb][rg]);
                union { float f; u32 u; } c{p};
                u16 pb = (u16)((c.u + 0x8000u) >> 16);  // round-half-up, p>=0
                int row = quad * 4 + rg;
                int cgr = (nb * 2 + (l16 >> 3)) ^ (row & 7);
                Ps[wave * 1024 + row * 64 + cgr * 8 + (l16 & 7)] = pb;
            }
        }
        asm volatile("s_waitcnt lgkmcnt(0)" ::: "memory");

        bf16x8 pf0 = *(const bf16x8*)&Ps[wave * 1024 + l16 * 64 + sw8];
        bf16x8 pf1 = *(const bf16x8*)&Ps[wave * 1024 + l16 * 64 + (sw8 ^ 32)];

        // row sums: l += P . 1
        lsum = __builtin_amdgcn_mfma_f32_16x16x32_bf16(pf0, ones, lsum, 0, 0, 0);
        lsum = __builtin_amdgcn_mfma_f32_16x16x32_bf16(pf1, ones, lsum, 0, 0, 0);

        // O += P V
        #pragma unroll
        for (int db = 0; db < 4; db++) {
            int rbase = (db * 16 + l16) * 64;
            bf16x8 vf0 = *(const bf16x8*)&Vs[buf][rbase + sw8];
            bf16x8 vf1 = *(const bf16x8*)&Vs[buf][rbase + (sw8 ^ 32)];
            o[db] = __builtin_amdgcn_mfma_f32_16x16x32_bf16(pf0, vf0, o[db], 0, 0, 0);
            o[db] = __builtin_amdgcn_mfma_f32_16x16x32_bf16(pf1, vf1, o[db], 0, 0, 0);
        }
    }

    // epilogue: O / l -> ctx bf16
    float rl[4];
    #pragma unroll
    for (int rg = 0; rg < 4; rg++) rl[rg] = 1.0f / lsum[rg];
    #pragma unroll
    for (int db = 0; db < 4; db++) {
        #pragma unroll
        for (int rg = 0; rg < 4; rg++) {
            int row = qt * 64 + wave * 16 + quad * 4 + rg;
            int col = h * 64 + db * 16 + l16;
            ctx[(size_t)(b * 1024 + row) * 768 + col] = f2bf(o[db][rg] * rl[rg]);
        }
    }
}

// ---------------------------------------------------------------------------
extern "C" void kernel_launch(void* const* d_in, const int* in_sizes, int n_in,
                              void* d_out, int out_size, void* d_ws, size_t ws_size,
                              hipStream_t stream) {
    const float* x      = (const float*)d_in[0];  // [8,1024,768]
    const float* w_qkv  = (const float*)d_in[1];  // [768,2304]
    const float* w_proj = (const float*)d_in[2];  // [768,768]
    const float* b_proj = (const float*)d_in[3];  // [768]
    float* out = (float*)d_out;

    const int BN = 8192;     // B*N
    const int C = 768, C3 = 2304;
    const float CE = 0.18033688011112042f;  // 0.125 * log2(e)

    u16* Xb      = (u16*)d_ws;                       // 8192*768
    u16* Wqkv_t  = Xb + (size_t)BN * C;              // 2304*768
    u16* Wproj_t = Wqkv_t + (size_t)C3 * C;          // 768*768
    u16* QKV     = Wproj_t + (size_t)C * C;          // 8192*2304 (Q,K used)
    u16* Vt      = QKV + (size_t)BN * C3;            // 96*64*1024
    u16* Ctx     = Vt + (size_t)96 * 64 * 1024;      // 8192*768

    convert_bf16<<<(BN * C / 4 + 255) / 256, 256, 0, stream>>>(x, Xb, BN * C / 4);
    prep_weights<<<2304, 256, 0, stream>>>(w_qkv, w_proj, Wqkv_t, Wproj_t);

    gemm_qkv<768><<<dim3(C3 / 128, BN / 128), 256, 0, stream>>>(
        Xb, Wqkv_t, QKV, Vt, CE);

    attn_kernel<<<dim3(16, 96), 256, 0, stream>>>(QKV, Vt, Ctx);

    gemm_proj<768><<<dim3(C / 128, BN / 128), 256, 0, stream>>>(
        Ctx, Wproj_t, out, b_proj, BN, C);
}

// Round 8
// 197.203 us; speedup vs baseline: 1.2624x; 1.0123x over previous
//
#include <hip/hip_runtime.h>

typedef __bf16 bf16x8 __attribute__((ext_vector_type(8)));
typedef float f32x4 __attribute__((ext_vector_type(4)));
typedef float f32x16 __attribute__((ext_vector_type(16)));
typedef unsigned short u16;
typedef unsigned int u32;
typedef u16 u16x4 __attribute__((ext_vector_type(4)));

__device__ __forceinline__ u16 f2bf(float f) {
    union { float f; u32 u; } x{f};
    u32 r = x.u + 0x7FFFu + ((x.u >> 16) & 1u);  // RNE
    return (u16)(r >> 16);
}

__device__ __forceinline__ float ex2(float x) {
#if __has_builtin(__builtin_amdgcn_exp2f)
    return __builtin_amdgcn_exp2f(x);
#else
    return __expf(x * 0.6931471805599453f);
#endif
}

// async global->LDS, 16B per lane; LDS dest = wave-uniform base + lane*16
#define GLD16(g, l)                                                            \
    __builtin_amdgcn_global_load_lds(                                          \
        (const __attribute__((address_space(1))) u32*)(g),                     \
        (__attribute__((address_space(3))) u32*)(l), 16, 0, 0)

// ---------------------------------------------------------------------------
// Elementwise fp32 -> bf16 convert (x)
// ---------------------------------------------------------------------------
__global__ void convert_bf16(const float* __restrict__ src, u16* __restrict__ dst, int n4) {
    int i = blockIdx.x * blockDim.x + threadIdx.x;
    if (i < n4) {
        float4 f = *(const float4*)(src + (size_t)i * 4);
        u16x4 u = { f2bf(f.x), f2bf(f.y), f2bf(f.z), f2bf(f.w) };
        *(u16x4*)(dst + (size_t)i * 4) = u;
    }
}

// ---------------------------------------------------------------------------
// Both weight transposes in one kernel.
// ---------------------------------------------------------------------------
__global__ __launch_bounds__(256) void prep_weights(
    const float* __restrict__ wq, const float* __restrict__ wp,
    u16* __restrict__ WqT, u16* __restrict__ WpT)
{
    __shared__ u16 tile[32][33];
    int id = blockIdx.x;
    const float* src; u16* dst; int R, C, bx, by;
    if (id < 1728) { src = wq; dst = WqT; R = 768; C = 2304; bx = (id % 72) * 32; by = (id / 72) * 32; }
    else { id -= 1728; src = wp; dst = WpT; R = 768; C = 768; bx = (id % 24) * 32; by = (id / 24) * 32; }
    int x = threadIdx.x & 31, y = threadIdx.x >> 5;
    #pragma unroll
    for (int i = 0; i < 32; i += 8)
        tile[y + i][x] = f2bf(src[(size_t)(by + y + i) * C + bx + x]);
    __syncthreads();
    #pragma unroll
    for (int i = 0; i < 32; i += 8)
        dst[(size_t)(bx + y + i) * R + by + x] = tile[x][y + i];
}

// ---------------------------------------------------------------------------
// QKV GEMM (unchanged from R7): 128x128 tile, BK=64, XOR-granule swizzle,
// V-section writes Vt[bh][d][n] via operand swap.
// ---------------------------------------------------------------------------
template <int K>
__global__ __launch_bounds__(256) void gemm_qkv(
    const u16* __restrict__ A,
    const u16* __restrict__ Wt,
    u16* __restrict__ QKV,
    u16* __restrict__ Vt,
    float qscale)
{
    __shared__ __align__(16) u16 As[128 * 64];
    __shared__ __align__(16) u16 Bs[128 * 64];

    int tid = threadIdx.x;
    int wave = tid >> 6, lane = tid & 63;
    int quad = lane >> 4, l16 = lane & 15;
    int wm = (wave >> 1) * 64, wn = (wave & 1) * 64;
    int bm = blockIdx.y * 128, bn = blockIdx.x * 128;
    bool vsec = (bn >= 1536);

    f32x4 acc[4][4] = {};

    int srow = lane >> 3;
    int scg = ((lane & 7) ^ srow) * 8;
    const u16* Ap = A + (size_t)(bm + wave * 32 + srow) * K + scg;
    const u16* Bp = Wt + (size_t)(bn + wave * 32 + srow) * K + scg;

    int fg0 = (((0 * 4 + quad) ^ (l16 & 7)) * 8);
    int fg1 = (((1 * 4 + quad) ^ (l16 & 7)) * 8);

    for (int k0 = 0; k0 < K; k0 += 64) {
        #pragma unroll
        for (int j = 0; j < 4; j++) {
            GLD16(Ap + k0 + (size_t)j * 8 * K, &As[(wave * 32 + j * 8) * 64]);
            GLD16(Bp + k0 + (size_t)j * 8 * K, &Bs[(wave * 32 + j * 8) * 64]);
        }
        __syncthreads();

        #pragma unroll
        for (int h = 0; h < 2; h++) {
            int fg = h ? fg1 : fg0;
            bf16x8 af[4], bfr[4];
            #pragma unroll
            for (int i = 0; i < 4; i++) {
                af[i]  = *(const bf16x8*)&As[(wm + i * 16 + l16) * 64 + fg];
                bfr[i] = *(const bf16x8*)&Bs[(wn + i * 16 + l16) * 64 + fg];
            }
            if (!vsec) {
                #pragma unroll
                for (int mi = 0; mi < 4; mi++)
                    #pragma unroll
                    for (int ni = 0; ni < 4; ni++)
                        acc[mi][ni] = __builtin_amdgcn_mfma_f32_16x16x32_bf16(af[mi], bfr[ni], acc[mi][ni], 0, 0, 0);
            } else {
                #pragma unroll
                for (int mi = 0; mi < 4; mi++)
                    #pragma unroll
                    for (int ni = 0; ni < 4; ni++)
                        acc[mi][ni] = __builtin_amdgcn_mfma_f32_16x16x32_bf16(bfr[ni], af[mi], acc[mi][ni], 0, 0, 0);
            }
        }
        __syncthreads();
    }

    if (!vsec) {
        #pragma unroll
        for (int mi = 0; mi < 4; mi++) {
            #pragma unroll
            for (int ni = 0; ni < 4; ni++) {
                #pragma unroll
                for (int rg = 0; rg < 4; rg++) {
                    int row = bm + wm + mi * 16 + quad * 4 + rg;
                    int col = bn + wn + ni * 16 + l16;
                    float sc = (col < 768) ? qscale : 1.0f;
                    QKV[(size_t)row * 2304 + col] = f2bf(acc[mi][ni][rg] * sc);
                }
            }
        }
    } else {
        #pragma unroll
        for (int mi = 0; mi < 4; mi++) {
            #pragma unroll
            for (int ni = 0; ni < 4; ni++) {
                #pragma unroll
                for (int rg = 0; rg < 4; rg++) {
                    int d = (bn - 1536) + wn + ni * 16 + quad * 4 + rg;
                    int ng = bm + wm + mi * 16 + l16;
                    int b = ng >> 10, n = ng & 1023, h = d >> 6;
                    Vt[((size_t)(b * 12 + h) * 64 + (d & 63)) * 1024 + n] = f2bf(acc[mi][ni][rg]);
                }
            }
        }
    }
}

// ---------------------------------------------------------------------------
// Output projection GEMM (unchanged from R7).
// ---------------------------------------------------------------------------
template <int K>
__global__ __launch_bounds__(256) void gemm_proj(
    const u16* __restrict__ A,
    const u16* __restrict__ Bt,
    float* __restrict__ Cp,
    const float* __restrict__ bias,
    int M, int N)
{
    __shared__ __align__(16) u16 As[128 * 64];
    __shared__ __align__(16) u16 Bs[128 * 64];

    int tid = threadIdx.x;
    int wave = tid >> 6, lane = tid & 63;
    int quad = lane >> 4, l16 = lane & 15;
    int wm = (wave >> 1) * 64, wn = (wave & 1) * 64;
    int bm = blockIdx.y * 128, bn = blockIdx.x * 128;

    f32x4 acc[4][4] = {};

    int srow = lane >> 3;
    int scg = ((lane & 7) ^ srow) * 8;
    const u16* Ap = A + (size_t)(bm + wave * 32 + srow) * K + scg;
    const u16* Bp = Bt + (size_t)(bn + wave * 32 + srow) * K + scg;

    int fg0 = (((0 * 4 + quad) ^ (l16 & 7)) * 8);
    int fg1 = (((1 * 4 + quad) ^ (l16 & 7)) * 8);

    for (int k0 = 0; k0 < K; k0 += 64) {
        #pragma unroll
        for (int j = 0; j < 4; j++) {
            GLD16(Ap + k0 + (size_t)j * 8 * K, &As[(wave * 32 + j * 8) * 64]);
            GLD16(Bp + k0 + (size_t)j * 8 * K, &Bs[(wave * 32 + j * 8) * 64]);
        }
        __syncthreads();

        #pragma unroll
        for (int h = 0; h < 2; h++) {
            int fg = h ? fg1 : fg0;
            bf16x8 af[4], bfr[4];
            #pragma unroll
            for (int i = 0; i < 4; i++) {
                af[i]  = *(const bf16x8*)&As[(wm + i * 16 + l16) * 64 + fg];
                bfr[i] = *(const bf16x8*)&Bs[(wn + i * 16 + l16) * 64 + fg];
            }
            #pragma unroll
            for (int mi = 0; mi < 4; mi++)
                #pragma unroll
                for (int ni = 0; ni < 4; ni++)
                    acc[mi][ni] = __builtin_amdgcn_mfma_f32_16x16x32_bf16(af[mi], bfr[ni], acc[mi][ni], 0, 0, 0);
        }
        __syncthreads();
    }

    #pragma unroll
    for (int mi = 0; mi < 4; mi++) {
        #pragma unroll
        for (int ni = 0; ni < 4; ni++) {
            #pragma unroll
            for (int rg = 0; rg < 4; rg++) {
                int row = bm + wm + mi * 16 + quad * 4 + rg;
                int col = bn + wn + ni * 16 + l16;
                Cp[(size_t)row * N + col] = acc[mi][ni][rg] + bias[col];
            }
        }
    }
}

// ---------------------------------------------------------------------------
// Flash attention v3: 32x32x16 MFMA. grid (8 q-tiles x 128 rows, 96 bh),
// 256 thr = 4 waves x 32 Q rows sharing one K/V tile (halves LDS operand
// traffic per q-row vs 16x16). Fixed-max softmax, lsum via ones-MFMA,
// double-buffered async K/V staging, XOR-granule swizzle everywhere,
// per-wave P roundtrip (no barrier). Q pre-scaled by 0.125*log2e.
// C-layout 32x32: col=lane&31, row=(reg&3)+8*(reg>>2)+4*(lane>>5).
// ---------------------------------------------------------------------------
__global__ __launch_bounds__(256, 3) void attn_kernel(
    const u16* __restrict__ qkv,
    const u16* __restrict__ Vt,
    u16* __restrict__ ctx)
{
    __shared__ __align__(16) u16 Ks[2][4096];   // 2 x 64key x 64d (swizzled)
    __shared__ __align__(16) u16 Vs[2][4096];   // 2 x 64d x 64key (swizzled)
    __shared__ __align__(16) u16 Ps[8192];      // 4 waves x 32q x 64key (swizzled)

    int qt = blockIdx.x;            // 0..7 (128 q rows per block)
    int bh = blockIdx.y;            // 0..95
    int b = bh / 12, h = bh % 12;
    int tid = threadIdx.x;
    int wave = tid >> 6, lane = tid & 63;
    int l32 = lane & 31, half = lane >> 5;
    int l7 = lane & 7;

    // Q A-fragments: m = l32 (within wave's 32 rows), k(d) = ks*16 + half*8 + j
    const u16* qbase = qkv + (size_t)(b * 1024 + qt * 128 + wave * 32 + l32) * 2304 + h * 64;
    bf16x8 qa[4];
    #pragma unroll
    for (int ks = 0; ks < 4; ks++)
        qa[ks] = *(const bf16x8*)(qbase + ks * 16 + half * 8);

    // staging addresses (row = lane>>3, dgroup = (lane&7) ^ row)
    int srow = lane >> 3;
    int scol = (lane & 7) ^ srow;
    const u16* kA = qkv + (size_t)(b * 1024 + wave * 16 + srow) * 2304 + 768 + h * 64 + scol * 8;
    const u16* vA = Vt + ((size_t)bh * 64 + wave * 16 + srow) * 1024 + scol * 8;

    bf16x8 ones;
    #pragma unroll
    for (int j = 0; j < 8; j++) ((u16*)&ones)[j] = 0x3F80;  // bf16 1.0

    f32x16 o0 = {}, o1 = {}, lsum = {};

    // swizzled fragment granule offsets: granule (ks*2 + half) ^ (l32&7)
    int fgo[4];
    #pragma unroll
    for (int ks = 0; ks < 4; ks++)
        fgo[ks] = (((ks * 2 + half) ^ l7) * 8);

    // prologue: stage tile 0 into buf 0
    {
        GLD16(kA,            &Ks[0][(wave * 2 + 0) * 512]);
        GLD16(kA + 8 * 2304, &Ks[0][(wave * 2 + 1) * 512]);
        GLD16(vA,            &Vs[0][(wave * 2 + 0) * 512]);
        GLD16(vA + 8 * 1024, &Vs[0][(wave * 2 + 1) * 512]);
    }

    #pragma unroll 2
    for (int kt = 0; kt < 16; kt++) {
        int buf = kt & 1;
        __syncthreads();   // drains vmcnt(0): buf is populated

        if (kt < 15) {     // prefetch next tile into the other buffer
            const u16* k0 = kA + (size_t)(kt + 1) * (64 * 2304);
            const u16* v0 = vA + (size_t)(kt + 1) * 64;
            GLD16(k0,            &Ks[buf ^ 1][(wave * 2 + 0) * 512]);
            GLD16(k0 + 8 * 2304, &Ks[buf ^ 1][(wave * 2 + 1) * 512]);
            GLD16(v0,            &Vs[buf ^ 1][(wave * 2 + 0) * 512]);
            GLD16(v0 + 8 * 1024, &Vs[buf ^ 1][(wave * 2 + 1) * 512]);
        }

        // S = Q K^T: s0 = keys 0..31, s1 = keys 32..63
        f32x16 s0 = {}, s1 = {};
        #pragma unroll
        for (int ks = 0; ks < 4; ks++) {
            bf16x8 k0 = *(const bf16x8*)&Ks[buf][(l32)      * 64 + fgo[ks]];
            bf16x8 k1 = *(const bf16x8*)&Ks[buf][(32 + l32) * 64 + fgo[ks]];
            s0 = __builtin_amdgcn_mfma_f32_32x32x16_bf16(qa[ks], k0, s0, 0, 0, 0);
            s1 = __builtin_amdgcn_mfma_f32_32x32x16_bf16(qa[ks], k1, s1, 0, 0, 0);
        }

        // P = exp2(S) -> per-wave swizzled Ps[32q][64key]
        int k3a = l32 >> 3;          // key granule low (keys 0..31): 0..3
        #pragma unroll
        for (int nb = 0; nb < 2; nb++) {
            int kg = nb * 4 + k3a;
            #pragma unroll
            for (int reg = 0; reg < 16; reg++) {
                float sv = nb ? s1[reg] : s0[reg];
                float p = ex2(sv);
                union { float f; u32 u; } c{p};
                u16 pb = (u16)((c.u + 0x8000u) >> 16);  // round-half-up, p>=0
                int row = (reg & 3) + 8 * (reg >> 2) + 4 * half;
                Ps[wave * 2048 + row * 64 + ((kg ^ (row & 7)) * 8) + l7] = pb;
            }
        }
        // per-wave LDS ordering: writes complete before reads (no barrier)
        asm volatile("s_waitcnt lgkmcnt(0)" ::: "memory");

        // lsum += P.1 ; O += P V
        #pragma unroll
        for (int ks = 0; ks < 4; ks++) {
            bf16x8 pf = *(const bf16x8*)&Ps[wave * 2048 + l32 * 64 + fgo[ks]];
            bf16x8 v0 = *(const bf16x8*)&Vs[buf][(l32)      * 64 + fgo[ks]];
            bf16x8 v1 = *(const bf16x8*)&Vs[buf][(32 + l32) * 64 + fgo[ks]];
            lsum = __builtin_amdgcn_mfma_f32_32x32x16_bf16(pf, ones, lsum, 0, 0, 0);
            o0   = __builtin_amdgcn_mfma_f32_32x32x16_bf16(pf, v0, o0, 0, 0, 0);
            o1   = __builtin_amdgcn_mfma_f32_32x32x16_bf16(pf, v1, o1, 0, 0, 0);
        }
    }

    // epilogue: O / l -> ctx bf16
    #pragma unroll
    for (int reg = 0; reg < 16; reg++) {
        float inv = 1.0f / lsum[reg];
        int row = (reg & 3) + 8 * (reg >> 2) + 4 * half;
        int qrow = qt * 128 + wave * 32 + row;
        size_t base = (size_t)(b * 1024 + qrow) * 768 + h * 64 + l32;
        ctx[base]      = f2bf(o0[reg] * inv);
        ctx[base + 32] = f2bf(o1[reg] * inv);
    }
}

// ---------------------------------------------------------------------------
extern "C" void kernel_launch(void* const* d_in, const int* in_sizes, int n_in,
                              void* d_out, int out_size, void* d_ws, size_t ws_size,
                              hipStream_t stream) {
    const float* x      = (const float*)d_in[0];  // [8,1024,768]
    const float* w_qkv  = (const float*)d_in[1];  // [768,2304]
    const float* w_proj = (const float*)d_in[2];  // [768,768]
    const float* b_proj = (const float*)d_in[3];  // [768]
    float* out = (float*)d_out;

    const int BN = 8192;     // B*N
    const int C = 768, C3 = 2304;
    const float CE = 0.18033688011112042f;  // 0.125 * log2(e)

    u16* Xb      = (u16*)d_ws;                       // 8192*768
    u16* Wqkv_t  = Xb + (size_t)BN * C;              // 2304*768
    u16* Wproj_t = Wqkv_t + (size_t)C3 * C;          // 768*768
    u16* QKV     = Wproj_t + (size_t)C * C;          // 8192*2304 (Q,K used)
    u16* Vt      = QKV + (size_t)BN * C3;            // 96*64*1024
    u16* Ctx     = Vt + (size_t)96 * 64 * 1024;      // 8192*768

    convert_bf16<<<(BN * C / 4 + 255) / 256, 256, 0, stream>>>(x, Xb, BN * C / 4);
    prep_weights<<<2304, 256, 0, stream>>>(w_qkv, w_proj, Wqkv_t, Wproj_t);

    gemm_qkv<768><<<dim3(C3 / 128, BN / 128), 256, 0, stream>>>(
        Xb, Wqkv_t, QKV, Vt, CE);

    attn_kernel<<<dim3(8, 96), 256, 0, stream>>>(QKV, Vt, Ctx);

    gemm_proj<768><<<dim3(C / 128, BN / 128), 256, 0, stream>>>(
        Ctx, Wproj_t, out, b_proj, BN, C);
}

// Round 9
// 195.470 us; speedup vs baseline: 1.2736x; 1.0089x over previous
//
#include <hip/hip_runtime.h>

typedef __bf16 bf16x8 __attribute__((ext_vector_type(8)));
typedef float f32x4 __attribute__((ext_vector_type(4)));
typedef float f32x16 __attribute__((ext_vector_type(16)));
typedef unsigned short u16;
typedef unsigned int u32;
typedef u16 u16x4 __attribute__((ext_vector_type(4)));
typedef u32 u32x4 __attribute__((ext_vector_type(4)));

__device__ __forceinline__ u16 f2bf(float f) {
    union { float f; u32 u; } x{f};
    u32 r = x.u + 0x7FFFu + ((x.u >> 16) & 1u);  // RNE
    return (u16)(r >> 16);
}

__device__ __forceinline__ float ex2(float x) {
#if __has_builtin(__builtin_amdgcn_exp2f)
    return __builtin_amdgcn_exp2f(x);
#else
    return __expf(x * 0.6931471805599453f);
#endif
}

// round-half-up bf16 (inputs >= 0), packed pair into u32
__device__ __forceinline__ u32 pkbf(float a, float b) {
    union { float f; u32 u; } ca{a}, cb{b};
    return ((ca.u + 0x8000u) >> 16) | (((cb.u + 0x8000u) >> 16) << 16);
}

// async global->LDS, 16B per lane; LDS dest = wave-uniform base + lane*16
#define GLD16(g, l)                                                            \
    __builtin_amdgcn_global_load_lds(                                          \
        (const __attribute__((address_space(1))) u32*)(g),                     \
        (__attribute__((address_space(3))) u32*)(l), 16, 0, 0)

// ---------------------------------------------------------------------------
// Elementwise fp32 -> bf16 convert (x)
// ---------------------------------------------------------------------------
__global__ void convert_bf16(const float* __restrict__ src, u16* __restrict__ dst, int n4) {
    int i = blockIdx.x * blockDim.x + threadIdx.x;
    if (i < n4) {
        float4 f = *(const float4*)(src + (size_t)i * 4);
        u16x4 u = { f2bf(f.x), f2bf(f.y), f2bf(f.z), f2bf(f.w) };
        *(u16x4*)(dst + (size_t)i * 4) = u;
    }
}

// ---------------------------------------------------------------------------
// Both weight transposes in one kernel.
// ---------------------------------------------------------------------------
__global__ __launch_bounds__(256) void prep_weights(
    const float* __restrict__ wq, const float* __restrict__ wp,
    u16* __restrict__ WqT, u16* __restrict__ WpT)
{
    __shared__ u16 tile[32][33];
    int id = blockIdx.x;
    const float* src; u16* dst; int R, C, bx, by;
    if (id < 1728) { src = wq; dst = WqT; R = 768; C = 2304; bx = (id % 72) * 32; by = (id / 72) * 32; }
    else { id -= 1728; src = wp; dst = WpT; R = 768; C = 768; bx = (id % 24) * 32; by = (id / 24) * 32; }
    int x = threadIdx.x & 31, y = threadIdx.x >> 5;
    #pragma unroll
    for (int i = 0; i < 32; i += 8)
        tile[y + i][x] = f2bf(src[(size_t)(by + y + i) * C + bx + x]);
    __syncthreads();
    #pragma unroll
    for (int i = 0; i < 32; i += 8)
        dst[(size_t)(bx + y + i) * R + by + x] = tile[x][y + i];
}

// ---------------------------------------------------------------------------
// QKV GEMM (unchanged from R7/R8): 128x128 tile, BK=64, XOR-granule swizzle,
// V-section writes Vt[bh][d][n] via operand swap.
// ---------------------------------------------------------------------------
template <int K>
__global__ __launch_bounds__(256) void gemm_qkv(
    const u16* __restrict__ A,
    const u16* __restrict__ Wt,
    u16* __restrict__ QKV,
    u16* __restrict__ Vt,
    float qscale)
{
    __shared__ __align__(16) u16 As[128 * 64];
    __shared__ __align__(16) u16 Bs[128 * 64];

    int tid = threadIdx.x;
    int wave = tid >> 6, lane = tid & 63;
    int quad = lane >> 4, l16 = lane & 15;
    int wm = (wave >> 1) * 64, wn = (wave & 1) * 64;
    int bm = blockIdx.y * 128, bn = blockIdx.x * 128;
    bool vsec = (bn >= 1536);

    f32x4 acc[4][4] = {};

    int srow = lane >> 3;
    int scg = ((lane & 7) ^ srow) * 8;
    const u16* Ap = A + (size_t)(bm + wave * 32 + srow) * K + scg;
    const u16* Bp = Wt + (size_t)(bn + wave * 32 + srow) * K + scg;

    int fg0 = (((0 * 4 + quad) ^ (l16 & 7)) * 8);
    int fg1 = (((1 * 4 + quad) ^ (l16 & 7)) * 8);

    for (int k0 = 0; k0 < K; k0 += 64) {
        #pragma unroll
        for (int j = 0; j < 4; j++) {
            GLD16(Ap + k0 + (size_t)j * 8 * K, &As[(wave * 32 + j * 8) * 64]);
            GLD16(Bp + k0 + (size_t)j * 8 * K, &Bs[(wave * 32 + j * 8) * 64]);
        }
        __syncthreads();

        #pragma unroll
        for (int h = 0; h < 2; h++) {
            int fg = h ? fg1 : fg0;
            bf16x8 af[4], bfr[4];
            #pragma unroll
            for (int i = 0; i < 4; i++) {
                af[i]  = *(const bf16x8*)&As[(wm + i * 16 + l16) * 64 + fg];
                bfr[i] = *(const bf16x8*)&Bs[(wn + i * 16 + l16) * 64 + fg];
            }
            if (!vsec) {
                #pragma unroll
                for (int mi = 0; mi < 4; mi++)
                    #pragma unroll
                    for (int ni = 0; ni < 4; ni++)
                        acc[mi][ni] = __builtin_amdgcn_mfma_f32_16x16x32_bf16(af[mi], bfr[ni], acc[mi][ni], 0, 0, 0);
            } else {
                #pragma unroll
                for (int mi = 0; mi < 4; mi++)
                    #pragma unroll
                    for (int ni = 0; ni < 4; ni++)
                        acc[mi][ni] = __builtin_amdgcn_mfma_f32_16x16x32_bf16(bfr[ni], af[mi], acc[mi][ni], 0, 0, 0);
            }
        }
        __syncthreads();
    }

    if (!vsec) {
        #pragma unroll
        for (int mi = 0; mi < 4; mi++) {
            #pragma unroll
            for (int ni = 0; ni < 4; ni++) {
                #pragma unroll
                for (int rg = 0; rg < 4; rg++) {
                    int row = bm + wm + mi * 16 + quad * 4 + rg;
                    int col = bn + wn + ni * 16 + l16;
                    float sc = (col < 768) ? qscale : 1.0f;
                    QKV[(size_t)row * 2304 + col] = f2bf(acc[mi][ni][rg] * sc);
                }
            }
        }
    } else {
        #pragma unroll
        for (int mi = 0; mi < 4; mi++) {
            #pragma unroll
            for (int ni = 0; ni < 4; ni++) {
                #pragma unroll
                for (int rg = 0; rg < 4; rg++) {
                    int d = (bn - 1536) + wn + ni * 16 + quad * 4 + rg;
                    int ng = bm + wm + mi * 16 + l16;
                    int b = ng >> 10, n = ng & 1023, h = d >> 6;
                    Vt[((size_t)(b * 12 + h) * 64 + (d & 63)) * 1024 + n] = f2bf(acc[mi][ni][rg]);
                }
            }
        }
    }
}

// ---------------------------------------------------------------------------
// Output projection GEMM (unchanged).
// ---------------------------------------------------------------------------
template <int K>
__global__ __launch_bounds__(256) void gemm_proj(
    const u16* __restrict__ A,
    const u16* __restrict__ Bt,
    float* __restrict__ Cp,
    const float* __restrict__ bias,
    int M, int N)
{
    __shared__ __align__(16) u16 As[128 * 64];
    __shared__ __align__(16) u16 Bs[128 * 64];

    int tid = threadIdx.x;
    int wave = tid >> 6, lane = tid & 63;
    int quad = lane >> 4, l16 = lane & 15;
    int wm = (wave >> 1) * 64, wn = (wave & 1) * 64;
    int bm = blockIdx.y * 128, bn = blockIdx.x * 128;

    f32x4 acc[4][4] = {};

    int srow = lane >> 3;
    int scg = ((lane & 7) ^ srow) * 8;
    const u16* Ap = A + (size_t)(bm + wave * 32 + srow) * K + scg;
    const u16* Bp = Bt + (size_t)(bn + wave * 32 + srow) * K + scg;

    int fg0 = (((0 * 4 + quad) ^ (l16 & 7)) * 8);
    int fg1 = (((1 * 4 + quad) ^ (l16 & 7)) * 8);

    for (int k0 = 0; k0 < K; k0 += 64) {
        #pragma unroll
        for (int j = 0; j < 4; j++) {
            GLD16(Ap + k0 + (size_t)j * 8 * K, &As[(wave * 32 + j * 8) * 64]);
            GLD16(Bp + k0 + (size_t)j * 8 * K, &Bs[(wave * 32 + j * 8) * 64]);
        }
        __syncthreads();

        #pragma unroll
        for (int h = 0; h < 2; h++) {
            int fg = h ? fg1 : fg0;
            bf16x8 af[4], bfr[4];
            #pragma unroll
            for (int i = 0; i < 4; i++) {
                af[i]  = *(const bf16x8*)&As[(wm + i * 16 + l16) * 64 + fg];
                bfr[i] = *(const bf16x8*)&Bs[(wn + i * 16 + l16) * 64 + fg];
            }
            #pragma unroll
            for (int mi = 0; mi < 4; mi++)
                #pragma unroll
                for (int ni = 0; ni < 4; ni++)
                    acc[mi][ni] = __builtin_amdgcn_mfma_f32_16x16x32_bf16(af[mi], bfr[ni], acc[mi][ni], 0, 0, 0);
        }
        __syncthreads();
    }

    #pragma unroll
    for (int mi = 0; mi < 4; mi++) {
        #pragma unroll
        for (int ni = 0; ni < 4; ni++) {
            #pragma unroll
            for (int rg = 0; rg < 4; rg++) {
                int row = bm + wm + mi * 16 + quad * 4 + rg;
                int col = bn + wn + ni * 16 + l16;
                Cp[(size_t)row * N + col] = acc[mi][ni][rg] + bias[col];
            }
        }
    }
}

// ---------------------------------------------------------------------------
// Flash attention v4: 32x32x16 MFMA, NO P LDS roundtrip.
// S^T = mfma(K,Q) -> C-layout has col=lane&31 = q, rows = keys; after exp,
// each lane holds its q's keys. Key-quads interleave across lane halves:
// half0 lanes hold quads {0,2} (+8k), half1 hold {1,3}. Four
// __shfl_xor(.,32) per 32-key tile exchange the partner quads, assembling
// PV A-fragments entirely in registers. LDS = K/V tiles only (32 KB).
// Fixed-max softmax, lsum via ones-MFMA, double-buffered async staging,
// XOR-granule swizzle. Q pre-scaled by 0.125*log2e; p = exp2(qk).
// ---------------------------------------------------------------------------
__global__ __launch_bounds__(256, 4) void attn_kernel(
    const u16* __restrict__ qkv,
    const u16* __restrict__ Vt,
    u16* __restrict__ ctx)
{
    __shared__ __align__(16) u16 Ks[2][4096];   // 2 x 64key x 64d (swizzled)
    __shared__ __align__(16) u16 Vs[2][4096];   // 2 x 64d x 64key (swizzled)

    int qt = blockIdx.x;            // 0..7 (128 q rows per block)
    int bh = blockIdx.y;            // 0..95
    int b = bh / 12, h = bh % 12;
    int tid = threadIdx.x;
    int wave = tid >> 6, lane = tid & 63;
    int l32 = lane & 31, half = lane >> 5;

    // Q fragments: lane holds q = l32, d = ks*16 + half*8 + j  (A/B layout)
    const u16* qbase = qkv + (size_t)(b * 1024 + qt * 128 + wave * 32 + l32) * 2304 + h * 64;
    bf16x8 qa[4];
    #pragma unroll
    for (int ks = 0; ks < 4; ks++)
        qa[ks] = *(const bf16x8*)(qbase + ks * 16 + half * 8);

    // staging addresses (row = lane>>3, dgroup = (lane&7) ^ row)
    int srow = lane >> 3;
    int scol = (lane & 7) ^ srow;
    const u16* kA = qkv + (size_t)(b * 1024 + wave * 16 + srow) * 2304 + 768 + h * 64 + scol * 8;
    const u16* vA = Vt + ((size_t)bh * 64 + wave * 16 + srow) * 1024 + scol * 8;

    bf16x8 ones;
    #pragma unroll
    for (int j = 0; j < 8; j++) ((u16*)&ones)[j] = 0x3F80;  // bf16 1.0

    f32x16 o0 = {}, o1 = {}, lsum = {};

    // swizzled fragment granule offsets: granule (ks*2 + half) ^ (row&7)
    int fgo[4];
    #pragma unroll
    for (int ks = 0; ks < 4; ks++)
        fgo[ks] = (((ks * 2 + half) ^ (lane & 7)) * 8);

    // prologue: stage tile 0 into buf 0
    {
        GLD16(kA,            &Ks[0][(wave * 2 + 0) * 512]);
        GLD16(kA + 8 * 2304, &Ks[0][(wave * 2 + 1) * 512]);
        GLD16(vA,            &Vs[0][(wave * 2 + 0) * 512]);
        GLD16(vA + 8 * 1024, &Vs[0][(wave * 2 + 1) * 512]);
    }

    #pragma unroll 2
    for (int kt = 0; kt < 16; kt++) {
        int buf = kt & 1;
        __syncthreads();   // drains vmcnt(0): buf is populated

        if (kt < 15) {     // prefetch next tile into the other buffer
            const u16* k0 = kA + (size_t)(kt + 1) * (64 * 2304);
            const u16* v0 = vA + (size_t)(kt + 1) * 64;
            GLD16(k0,            &Ks[buf ^ 1][(wave * 2 + 0) * 512]);
            GLD16(k0 + 8 * 2304, &Ks[buf ^ 1][(wave * 2 + 1) * 512]);
            GLD16(v0,            &Vs[buf ^ 1][(wave * 2 + 0) * 512]);
            GLD16(v0 + 8 * 1024, &Vs[buf ^ 1][(wave * 2 + 1) * 512]);
        }

        // S^T = K Q^T : st0 = keys 0..31, st1 = keys 32..63 (col = q = l32)
        f32x16 st0 = {}, st1 = {};
        #pragma unroll
        for (int ks = 0; ks < 4; ks++) {
            bf16x8 kf0 = *(const bf16x8*)&Ks[buf][(l32)      * 64 + fgo[ks]];
            bf16x8 kf1 = *(const bf16x8*)&Ks[buf][(32 + l32) * 64 + fgo[ks]];
            st0 = __builtin_amdgcn_mfma_f32_32x32x16_bf16(kf0, qa[ks], st0, 0, 0, 0);
            st1 = __builtin_amdgcn_mfma_f32_32x32x16_bf16(kf1, qa[ks], st1, 0, 0, 0);
        }

        // exp2 + pack + half-exchange -> PV A-frags pf[0..3] (keys 16ks..+15)
        bf16x8 pf[4];
        #pragma unroll
        for (int t = 0; t < 2; t++) {
            u32 pk[8];
            #pragma unroll
            for (int g = 0; g < 4; g++) {
                float p0 = ex2(t ? st1[4 * g + 0] : st0[4 * g + 0]);
                float p1 = ex2(t ? st1[4 * g + 1] : st0[4 * g + 1]);
                float p2 = ex2(t ? st1[4 * g + 2] : st0[4 * g + 2]);
                float p3 = ex2(t ? st1[4 * g + 3] : st0[4 * g + 3]);
                pk[2 * g + 0] = pkbf(p0, p1);
                pk[2 * g + 1] = pkbf(p2, p3);
            }
            // exchange partner quads across the half boundary
            u32 rA0 = __shfl_xor(half ? pk[0] : pk[2], 32);
            u32 rA1 = __shfl_xor(half ? pk[1] : pk[3], 32);
            u32 rB0 = __shfl_xor(half ? pk[4] : pk[6], 32);
            u32 rB1 = __shfl_xor(half ? pk[5] : pk[7], 32);
            u32x4 f0 = { half ? rA0 : pk[0], half ? rA1 : pk[1],
                         half ? pk[2] : rA0, half ? pk[3] : rA1 };
            u32x4 f1 = { half ? rB0 : pk[4], half ? rB1 : pk[5],
                         half ? pk[6] : rB0, half ? pk[7] : rB1 };
            union { u32x4 u; bf16x8 b; } c0{f0}, c1{f1};
            pf[2 * t + 0] = c0.b;
            pf[2 * t + 1] = c1.b;
        }

        // lsum += P.1 ; O += P V
        #pragma unroll
        for (int ks = 0; ks < 4; ks++) {
            bf16x8 v0f = *(const bf16x8*)&Vs[buf][(l32)      * 64 + fgo[ks]];
            bf16x8 v1f = *(const bf16x8*)&Vs[buf][(32 + l32) * 64 + fgo[ks]];
            lsum = __builtin_amdgcn_mfma_f32_32x32x16_bf16(pf[ks], ones, lsum, 0, 0, 0);
            o0   = __builtin_amdgcn_mfma_f32_32x32x16_bf16(pf[ks], v0f, o0, 0, 0, 0);
            o1   = __builtin_amdgcn_mfma_f32_32x32x16_bf16(pf[ks], v1f, o1, 0, 0, 0);
        }
    }

    // epilogue: O / l -> ctx bf16 (C-layout: col=d=l32, rows=q)
    #pragma unroll
    for (int reg = 0; reg < 16; reg++) {
        float inv = 1.0f / lsum[reg];
        int row = (reg & 3) + 8 * (reg >> 2) + 4 * half;
        int qrow = qt * 128 + wave * 32 + row;
        size_t base = (size_t)(b * 1024 + qrow) * 768 + h * 64 + l32;
        ctx[base]      = f2bf(o0[reg] * inv);
        ctx[base + 32] = f2bf(o1[reg] * inv);
    }
}

// ---------------------------------------------------------------------------
extern "C" void kernel_launch(void* const* d_in, const int* in_sizes, int n_in,
                              void* d_out, int out_size, void* d_ws, size_t ws_size,
                              hipStream_t stream) {
    const float* x      = (const float*)d_in[0];  // [8,1024,768]
    const float* w_qkv  = (const float*)d_in[1];  // [768,2304]
    const float* w_proj = (const float*)d_in[2];  // [768,768]
    const float* b_proj = (const float*)d_in[3];  // [768]
    float* out = (float*)d_out;

    const int BN = 8192;     // B*N
    const int C = 768, C3 = 2304;
    const float CE = 0.18033688011112042f;  // 0.125 * log2(e)

    u16* Xb      = (u16*)d_ws;                       // 8192*768
    u16* Wqkv_t  = Xb + (size_t)BN * C;              // 2304*768
    u16* Wproj_t = Wqkv_t + (size_t)C3 * C;          // 768*768
    u16* QKV     = Wproj_t + (size_t)C * C;          // 8192*2304 (Q,K used)
    u16* Vt      = QKV + (size_t)BN * C3;            // 96*64*1024
    u16* Ctx     = Vt + (size_t)96 * 64 * 1024;      // 8192*768

    convert_bf16<<<(BN * C / 4 + 255) / 256, 256, 0, stream>>>(x, Xb, BN * C / 4);
    prep_weights<<<2304, 256, 0, stream>>>(w_qkv, w_proj, Wqkv_t, Wproj_t);

    gemm_qkv<768><<<dim3(C3 / 128, BN / 128), 256, 0, stream>>>(
        Xb, Wqkv_t, QKV, Vt, CE);

    attn_kernel<<<dim3(8, 96), 256, 0, stream>>>(QKV, Vt, Ctx);

    gemm_proj<768><<<dim3(C / 128, BN / 128), 256, 0, stream>>>(
        Ctx, Wproj_t, out, b_proj, BN, C);
}